// Round 9
// baseline (141.846 us; speedup 1.0000x reference)
//
#include <hip/hip_runtime.h>

typedef short s16x8 __attribute__((ext_vector_type(8)));
typedef short s16x4 __attribute__((ext_vector_type(4)));
typedef float f32x4 __attribute__((ext_vector_type(4)));
typedef float f4 __attribute__((ext_vector_type(4)));
typedef unsigned short u16x4 __attribute__((ext_vector_type(4)));

#define CEXP 14.426950408889634074f   // 10 * log2(e)

__device__ __forceinline__ unsigned short f2bf(float f) {
    union { float f; unsigned int i; } v; v.f = f;
    unsigned int x = v.i;
    return (unsigned short)((x + 0x7fffu + ((x >> 16) & 1u)) >> 16);  // RNE
}
__device__ __forceinline__ float bf2f(unsigned short u) {
    union { unsigned int i; float f; } v; v.i = ((unsigned int)u) << 16; return v.f;
}

// pack 4 fp32 -> 4 bf16 (element order preserved)
__device__ __forceinline__ s16x4 pk_bf16x4(float p0, float p1, float p2, float p3) {
#if __has_builtin(__builtin_amdgcn_cvt_pk_bf16_f32)
    typedef __bf16 bf16x2 __attribute__((ext_vector_type(2)));
    union { struct { bf16x2 a, b; } h; s16x4 s; } r;
    r.h.a = __builtin_amdgcn_cvt_pk_bf16_f32(p0, p1);
    r.h.b = __builtin_amdgcn_cvt_pk_bf16_f32(p2, p3);
    return r.s;
#else
    unsigned u0 = __float_as_uint(p0) + 0x8000u;
    unsigned u1 = __float_as_uint(p1) + 0x8000u;
    unsigned u2 = __float_as_uint(p2) + 0x8000u;
    unsigned u3 = __float_as_uint(p3) + 0x8000u;
    union { uint2 u; s16x4 s; } pb;
    pb.u.x = __builtin_amdgcn_perm(u1, u0, 0x07060302u);
    pb.u.y = __builtin_amdgcn_perm(u3, u2, 0x07060302u);
    return pb.s;
#endif
}

__device__ __forceinline__ u16x4 pk4(f4 v) {
    u16x4 r = { f2bf(v[0]), f2bf(v[1]), f2bf(v[2]), f2bf(v[3]) };
    return r;
}

// global -> LDS direct DMA, 16B/lane.  HW semantics: LDS dest = wave-uniform
// base + lane*16 (exactly our staging layout); global src is per-lane.
__device__ __forceinline__ void gl_lds16(const void* g, void* l) {
    __builtin_amdgcn_global_load_lds(
        (const __attribute__((address_space(1))) void*)g,
        (__attribute__((address_space(3))) void*)l,
        16, 0, 0);
}

// ---------------------------------------------------------------------------
// k_prep v2 (unchanged): coalesced 64x64 LDS-tile transposes.
// ---------------------------------------------------------------------------
__global__ __launch_bounds__(256) void k_prep(
    const float* __restrict__ Wqkv, const float* __restrict__ Wout,
    unsigned short* __restrict__ Wt, unsigned short* __restrict__ WoT,
    float* __restrict__ sumsqp)
{
    __shared__ float tile[64][65];
    const int blk = blockIdx.x, tid = threadIdx.x;
    if (blk >= 16) {
        sumsqp[(blk - 16) * 256 + tid] = 0.f;     // 32 blocks x 256 = 8192
        return;
    }
    const float* src;
    unsigned short* dst;
    int lds_src, k0, n0;
    if (blk < 12) {
        src = Wqkv; dst = Wt; lds_src = 384;
        k0 = (blk & 1) * 64; n0 = (blk >> 1) * 64;
    } else {
        int b = blk - 12;
        src = Wout; dst = WoT; lds_src = 128;
        k0 = (b & 1) * 64; n0 = (b >> 1) * 64;
    }
    const int c = tid & 63, r0 = tid >> 6;
#pragma unroll
    for (int i = 0; i < 16; ++i) {
        int row = i * 4 + r0;
        tile[row][c] = src[(size_t)(k0 + row) * lds_src + n0 + c];
    }
    __syncthreads();
#pragma unroll
    for (int i = 0; i < 16; ++i) {
        int n = i * 4 + r0;
        dst[(size_t)(n0 + n) * 128 + k0 + c] = f2bf(tile[c][n]);
    }
}

// ---------------------------------------------------------------------------
// k_qkv v7 (unchanged from R19): 3-in-1, grid (256,2).
// ---------------------------------------------------------------------------
__global__ __launch_bounds__(256, 2) void k_qkv(
    const float* __restrict__ x, const unsigned short* __restrict__ Wt,
    unsigned short* __restrict__ Qb, unsigned short* __restrict__ Kb,
    unsigned short* __restrict__ Vt, float* __restrict__ sumsqp)
{
    __shared__ float red[4][64];
    const int tid = threadIdx.x;
    const int wl = tid >> 6, lane = tid & 63;
    const int qd = lane >> 4, nn = lane & 15;
    const int yb = blockIdx.y;                 // 0..1: 64-col half within category
    const int tw0 = blockIdx.x * 64 + wl * 16; // token base for this wave

    const float* apf = x + (size_t)(tw0 + nn) * 128 + qd * 8;
    s16x8 af[4];
#pragma unroll
    for (int ks = 0; ks < 4; ++ks) {
        f4 a0 = *(const f4*)(apf + ks * 32);
        f4 a1 = *(const f4*)(apf + ks * 32 + 4);
        union { struct { s16x4 lo, hi; } h; s16x8 v; } u;
        u.h.lo = pk_bf16x4(a0[0], a0[1], a0[2], a0[3]);
        u.h.hi = pk_bf16x4(a1[0], a1[1], a1[2], a1[3]);
        af[ks] = u.v;
    }

    const int b = tw0 >> 12;           // batch (block-uniform: 64 | 4096)
    const int tl0 = tw0 & 4095;        // token within batch
    const int tok = tl0 + nn;

    // ---- categories 0 (q) and 1 (k): A = W rows (out-cols), B = x rows ----
#pragma unroll
    for (int c = 0; c < 2; ++c) {
        const int n0 = c * 128 + yb * 64;
        const unsigned short* bp = Wt + (size_t)(n0 + nn) * 128 + qd * 8;
        s16x8 bfr[16];
#pragma unroll
        for (int nb = 0; nb < 4; ++nb)
#pragma unroll
            for (int ks = 0; ks < 4; ++ks)
                bfr[nb * 4 + ks] = *(const s16x8*)(bp + (size_t)nb * 2048 + ks * 32);

        f32x4 acc[4];
#pragma unroll
        for (int nb = 0; nb < 4; ++nb) acc[nb] = (f32x4){0.f, 0.f, 0.f, 0.f};
#pragma unroll
        for (int ks = 0; ks < 4; ++ks)
#pragma unroll
            for (int nb = 0; nb < 4; ++nb)
                acc[nb] = __builtin_amdgcn_mfma_f32_16x16x32_bf16(bfr[nb * 4 + ks], af[ks], acc[nb], 0, 0, 0);

        unsigned short* dst = (c == 0) ? Qb : Kb;
#pragma unroll
        for (int nb = 0; nb < 4; ++nb) {
            const int dim = yb * 64 + nb * 16 + qd * 4;      // 4-aligned, +r
            const int h = dim >> 5, d0 = dim & 31;
            *(u16x4*)&dst[(size_t)((b * 4 + h) * 4096 + tok) * 32 + d0] = pk4(acc[nb]);
            f32x4 ss;
#pragma unroll
            for (int r = 0; r < 4; ++r) ss[r] = acc[nb][r] * acc[nb][r];
#pragma unroll
            for (int m = 1; m < 16; m <<= 1) {
#pragma unroll
                for (int r = 0; r < 4; ++r) ss[r] += __shfl_xor(ss[r], m);
            }
            if (nn == 0)
                *(f4*)&red[wl][nb * 16 + qd * 4] = ss;       // slab partial
        }
        __syncthreads();                   // block-uniform: safe
        if (tid < 64) {
            float s = red[0][tid] + red[1][tid] + red[2][tid] + red[3][tid];
            const int g = (c << 9) + (b << 7) + yb * 64 + tid;
            atomicAdd(&sumsqp[((blockIdx.x & 7) << 10) + g], s);
        }
        __syncthreads();                   // red reused by next category
    }

    // ---- category 2 (v): A = x rows (tokens), B = W rows: D row = token ----
    {
        const int n0 = 256 + yb * 64;
        const unsigned short* bp = Wt + (size_t)(n0 + nn) * 128 + qd * 8;
        s16x8 bfr[16];
#pragma unroll
        for (int nb = 0; nb < 4; ++nb)
#pragma unroll
            for (int ks = 0; ks < 4; ++ks)
                bfr[nb * 4 + ks] = *(const s16x8*)(bp + (size_t)nb * 2048 + ks * 32);

        f32x4 acc[4];
#pragma unroll
        for (int nb = 0; nb < 4; ++nb) acc[nb] = (f32x4){0.f, 0.f, 0.f, 0.f};
#pragma unroll
        for (int ks = 0; ks < 4; ++ks)
#pragma unroll
            for (int nb = 0; nb < 4; ++nb)
                acc[nb] = __builtin_amdgcn_mfma_f32_16x16x32_bf16(af[ks], bfr[nb * 4 + ks], acc[nb], 0, 0, 0);
#pragma unroll
        for (int nb = 0; nb < 4; ++nb) {
            const int dim = yb * 64 + nb * 16 + nn;
            const int h = dim >> 5, d = dim & 31;
            *(u16x4*)&Vt[(size_t)((b * 4 + h) * 32 + d) * 4096 + tl0 + qd * 4] = pk4(acc[nb]);
        }
    }
}

// ---------------------------------------------------------------------------
// k_attn v16 = v13 body with staging moved to global_load_lds DMA (R20):
// v13's reg-staging paid 2 global->VGPR loads + 2 ds_write_b128 + a tail
// vmcnt wait per wave per jt.  Our LDS staging layout is exactly the DMA's
// HW pattern (wave-uniform base + lane*16), so the builtin is a drop-in:
// no register landing, no ds_write instructions, loads drain at the next
// barrier's compiler-emitted vmcnt(0) after a FULL compute phase of slack
// (~4350 cyc >> 900 cyc HBM latency).  Issue-after-barrier is race-free:
// buffer (jt+1)&1 was last read in jt-1, ordered by the barrier at jt.
// Removes ~20% of LDS-pipe work and the staging dependency chain; all
// compute, layouts and epilogue byte-identical to v13 (57.7us).
// ---------------------------------------------------------------------------
__global__ __launch_bounds__(512, 4) void k_attn(
    const unsigned short* __restrict__ Qb, const unsigned short* __restrict__ Kb,
    const unsigned short* __restrict__ Vt, const float* __restrict__ sumsqp,
    unsigned short* __restrict__ Ogb)
{
    __shared__ char smem[32768];
    const int tid  = threadIdx.x;
    const int wv   = tid >> 6, lane = tid & 63;
    const int wl   = wv & 3, half = wv >> 2;
    const int qd   = lane >> 4, nn = lane & 15;
    const int bh   = blockIdx.x;
    const int ib   = blockIdx.y * 128 + wl * 32;
    const unsigned short* Qbh = Qb + (size_t)bh * 4096 * 32;
    const unsigned short* Kbh = Kb + (size_t)bh * 4096 * 32;
    const unsigned short* Vbh = Vt + (size_t)bh * 32 * 4096;

    // rj[d] = min(rsqrt(ssq_q),1e12) * min(rsqrt(ssq_k),1e12) * CEXP
    float rj[8];
    {
        const int gq = bh * 32 + qd * 8;
#pragma unroll
        for (int j = 0; j < 8; ++j) {
            float sq = 0.f, sk = 0.f;
#pragma unroll
            for (int c = 0; c < 8; ++c) {
                sq += sumsqp[c * 1024 + gq + j];
                sk += sumsqp[c * 1024 + 512 + gq + j];
            }
            rj[j] = fminf(__builtin_amdgcn_rsqf(sq), 1e12f)
                  * fminf(__builtin_amdgcn_rsqf(sk), 1e12f) * CEXP;
        }
    }

    s16x8 q0r = *(const s16x8*)(Qbh + (ib + nn) * 32 + qd * 8);
    s16x8 q1r = *(const s16x8*)(Qbh + (ib + 16 + nn) * 32 + qd * 8);
    s16x8 qf0, qf1;
#pragma unroll
    for (int j = 0; j < 8; ++j) {
        qf0[j] = (short)f2bf(bf2f((unsigned short)q0r[j]) * rj[j]);
        qf1[j] = (short)f2bf(bf2f((unsigned short)q1r[j]) * rj[j]);
    }

    f32x4 o00 = {0.f,0.f,0.f,0.f}, o01 = {0.f,0.f,0.f,0.f};
    f32x4 o10 = {0.f,0.f,0.f,0.f}, o11 = {0.f,0.f,0.f,0.f};
    f32x4 la  = {0.f,0.f,0.f,0.f}, lb  = {0.f,0.f,0.f,0.f};
    const f32x4 zro = {0.f,0.f,0.f,0.f};
    const s16x8 ones8 = { (short)0x3F80, (short)0x3F80, (short)0x3F80, (short)0x3F80,
                          (short)0x3F80, (short)0x3F80, (short)0x3F80, (short)0x3F80 };

    const int KB0 = half * 8192;
    const int VB0 = 16384 + half * 8192;
    const int jb0 = half * 2048;

    // K staging: wave wl fills LDS tile wl, rows nn, j-permuted
    const int jperm = ((wl >> 1) << 5) + ((nn >> 2) << 3) + ((wl & 1) << 2) + (nn & 3);
    const unsigned short* ksrc = Kbh + (size_t)(jb0 + jperm) * 32 + qd * 8;
    // V staging: wave wl -> (dhalf=wl>>1, js32=wl&1); lane: d=nn, tok=qd*8..+7
    const unsigned short* vsrc = Vbh + (size_t)((wl >> 1) * 16 + nn) * 4096
                               + jb0 + (wl & 1) * 32 + qd * 8;
    // wave-uniform DMA dest bases (HW adds lane*16); buffers at +0 / +4096
    char* kbase = smem + KB0 + wl * 1024;
    char* vbase = smem + VB0 + wl * 1024;

    {   // preload tile 0 -> buffer 0 (drained by the loop's first barrier)
        gl_lds16(ksrc, kbase);
        gl_lds16(vsrc, vbase);
        ksrc += 2048; vsrc += 64;
    }

    for (int jt = 0; jt < 32; ++jt) {
        __syncthreads();   // drains DMA for buffer jt&1; buffer (jt+1)&1 free
        if (jt < 31) {
            const int nxt = ((jt + 1) & 1) * 4096;
            gl_lds16(ksrc, kbase + nxt);
            gl_lds16(vsrc, vbase + nxt);
            ksrc += 2048; vsrc += 64;
        }
        const char* kcur = smem + KB0 + (jt & 1) * 4096;
        const char* vcur = smem + VB0 + (jt & 1) * 4096;
#pragma unroll
        for (int js32 = 0; js32 < 2; ++js32) {
            s16x8 kf0 = *(const s16x8*)(kcur + (js32 * 2 + 0) * 1024 + lane * 16);
            s16x8 kf1 = *(const s16x8*)(kcur + (js32 * 2 + 1) * 1024 + lane * 16);
            f32x4 sa0 = __builtin_amdgcn_mfma_f32_16x16x32_bf16(kf0, qf0, zro, 0, 0, 0);
            f32x4 sb0 = __builtin_amdgcn_mfma_f32_16x16x32_bf16(kf0, qf1, zro, 0, 0, 0);
            f32x4 sa1 = __builtin_amdgcn_mfma_f32_16x16x32_bf16(kf1, qf0, zro, 0, 0, 0);
            f32x4 sb1 = __builtin_amdgcn_mfma_f32_16x16x32_bf16(kf1, qf1, zro, 0, 0, 0);
            float a0 = __builtin_amdgcn_exp2f(sa0[0]);
            float a1 = __builtin_amdgcn_exp2f(sa0[1]);
            float a2 = __builtin_amdgcn_exp2f(sa0[2]);
            float a3 = __builtin_amdgcn_exp2f(sa0[3]);
            float a4 = __builtin_amdgcn_exp2f(sa1[0]);
            float a5 = __builtin_amdgcn_exp2f(sa1[1]);
            float a6 = __builtin_amdgcn_exp2f(sa1[2]);
            float a7 = __builtin_amdgcn_exp2f(sa1[3]);
            float b0 = __builtin_amdgcn_exp2f(sb0[0]);
            float b1 = __builtin_amdgcn_exp2f(sb0[1]);
            float b2 = __builtin_amdgcn_exp2f(sb0[2]);
            float b3 = __builtin_amdgcn_exp2f(sb0[3]);
            float b4 = __builtin_amdgcn_exp2f(sb1[0]);
            float b5 = __builtin_amdgcn_exp2f(sb1[1]);
            float b6 = __builtin_amdgcn_exp2f(sb1[2]);
            float b7 = __builtin_amdgcn_exp2f(sb1[3]);
            union { struct { s16x4 lo, hi; } h; s16x8 v; } ua, ub;
            ua.h.lo = pk_bf16x4(a0, a1, a2, a3);
            ua.h.hi = pk_bf16x4(a4, a5, a6, a7);
            ub.h.lo = pk_bf16x4(b0, b1, b2, b3);
            ub.h.hi = pk_bf16x4(b4, b5, b6, b7);
            s16x8 pa32 = ua.v, pb32 = ub.v;
            la = __builtin_amdgcn_mfma_f32_16x16x32_bf16(ones8, pa32, la, 0, 0, 0);
            lb = __builtin_amdgcn_mfma_f32_16x16x32_bf16(ones8, pb32, lb, 0, 0, 0);
            s16x8 va = *(const s16x8*)(vcur + js32 * 1024 + lane * 16);
            s16x8 vb = *(const s16x8*)(vcur + 2048 + js32 * 1024 + lane * 16);
            o00 = __builtin_amdgcn_mfma_f32_16x16x32_bf16(va, pa32, o00, 0, 0, 0);
            o01 = __builtin_amdgcn_mfma_f32_16x16x32_bf16(vb, pa32, o01, 0, 0, 0);
            o10 = __builtin_amdgcn_mfma_f32_16x16x32_bf16(va, pb32, o10, 0, 0, 0);
            o11 = __builtin_amdgcn_mfma_f32_16x16x32_bf16(vb, pb32, o11, 0, 0, 0);
        }
    }

    const float lpa = la[0];   // replicated over r and qd; exact row-sum for i=nn
    const float lpb = lb[0];
    __syncthreads();                           // staging LDS dead now
    float* Ob = (float*)smem;                  // [4 wl][2 it][64 lane][8] = 16KB
    float* Lb = (float*)(smem + 16384);        // [4][2][64] = 2KB
    if (half) {
        float* d0 = Ob + ((wl * 2 + 0) * 64 + lane) * 8;
        *(f4*)d0 = o00; *(f4*)(d0 + 4) = o01;
        float* d1 = Ob + ((wl * 2 + 1) * 64 + lane) * 8;
        *(f4*)d1 = o10; *(f4*)(d1 + 4) = o11;
        Lb[(wl * 2 + 0) * 64 + lane] = lpa;
        Lb[(wl * 2 + 1) * 64 + lane] = lpb;
    }
    __syncthreads();
    if (!half) {
        const int bb = bh >> 2, hh = bh & 3;
        float* s0 = Ob + ((wl * 2 + 0) * 64 + lane) * 8;
        float rla = 1.f / (lpa + Lb[(wl * 2 + 0) * 64 + lane]);
        f4 m00 = (o00 + *(const f4*)s0) * rla;
        f4 m01 = (o01 + *(const f4*)(s0 + 4)) * rla;
        float* s1 = Ob + ((wl * 2 + 1) * 64 + lane) * 8;
        float rlb = 1.f / (lpb + Lb[(wl * 2 + 1) * 64 + lane]);
        f4 m10 = (o10 + *(const f4*)s1) * rlb;
        f4 m11 = (o11 + *(const f4*)(s1 + 4)) * rlb;
        unsigned short* dst0 = Ogb + (size_t)(bb * 4096 + blockIdx.y * 128 + wl * 32 + nn) * 128
                             + hh * 32 + qd * 4;
        *(u16x4*)dst0 = pk4(m00);
        *(u16x4*)(dst0 + 16) = pk4(m01);
        unsigned short* dst1 = dst0 + (size_t)16 * 128;
        *(u16x4*)dst1 = pk4(m10);
        *(u16x4*)(dst1 + 16) = pk4(m11);
    }
}

// ---------------------------------------------------------------------------
// k_out v1 (unchanged): out = Og @ W_out + b_out.
// ---------------------------------------------------------------------------
__global__ __launch_bounds__(256, 2) void k_out(
    const unsigned short* __restrict__ Ogb, const unsigned short* __restrict__ WoT,
    const float* __restrict__ bout, float* __restrict__ out)
{
    const int tid = threadIdx.x;
    const int wl = tid >> 6, lane = tid & 63;
    const int qd = lane >> 4, nn = lane & 15;
    const int n0 = blockIdx.y * 64;            // outc base
    const int tw0 = blockIdx.x * 64 + wl * 16; // token base

    const unsigned short* ap = WoT + (size_t)(n0 + nn) * 128 + qd * 8;
    const unsigned short* bp = Ogb + (size_t)(tw0 + nn) * 128 + qd * 8;
    s16x8 bfr[4], afr[16];
#pragma unroll
    for (int ks = 0; ks < 4; ++ks) bfr[ks] = *(const s16x8*)(bp + ks * 32);
#pragma unroll
    for (int nb = 0; nb < 4; ++nb)
#pragma unroll
        for (int ks = 0; ks < 4; ++ks)
            afr[nb * 4 + ks] = *(const s16x8*)(ap + (size_t)nb * 2048 + ks * 32);

    f32x4 acc[4];
#pragma unroll
    for (int nb = 0; nb < 4; ++nb) acc[nb] = (f32x4){0.f, 0.f, 0.f, 0.f};
#pragma unroll
    for (int ks = 0; ks < 4; ++ks)
#pragma unroll
        for (int nb = 0; nb < 4; ++nb)
            acc[nb] = __builtin_amdgcn_mfma_f32_16x16x32_bf16(afr[nb * 4 + ks], bfr[ks], acc[nb], 0, 0, 0);

#pragma unroll
    for (int nb = 0; nb < 4; ++nb) {
        const int c = n0 + nb * 16 + qd * 4;
        f4 bv = *(const f4*)&bout[c];
        f4 r;
#pragma unroll
        for (int j = 0; j < 4; ++j) r[j] = acc[nb][j] + bv[j];
        *(f4*)&out[(size_t)(tw0 + nn) * 128 + c] = r;
    }
}

// ---------------------------------------------------------------------------
extern "C" void kernel_launch(void* const* d_in, const int* in_sizes, int n_in,
                              void* d_out, int out_size, void* d_ws, size_t ws_size,
                              hipStream_t stream)
{
    const float* x    = (const float*)d_in[0];
    const float* Wqkv = (const float*)d_in[1];
    const float* Wout = (const float*)d_in[2];
    const float* bout = (const float*)d_in[3];
    float* out = (float*)d_out;
    char* ws = (char*)d_ws;
    const size_t MB = 1024 * 1024;
    unsigned short* Qb  = (unsigned short*)(ws);             // 4 MB [16][4096][32] (raw q)
    unsigned short* Kb  = (unsigned short*)(ws + 4 * MB);    // 4 MB (raw k)
    unsigned short* Vt  = (unsigned short*)(ws + 8 * MB);    // 4 MB [16][32][4096]
    unsigned short* Ogb = (unsigned short*)(ws + 12 * MB);   // 4 MB [16384][128] bf16
    unsigned short* Wt  = (unsigned short*)(ws + 16 * MB);               // 96 KB
    unsigned short* WoT = (unsigned short*)(ws + 16 * MB + 112 * 1024);  // 32 KB
    float*       sumsqp = (float*)(ws + 16 * MB + 160 * 1024);           // 32 KB [8][1024]

    hipLaunchKernelGGL(k_prep, dim3(48), dim3(256), 0, stream, Wqkv, Wout, Wt, WoT, sumsqp);
    hipLaunchKernelGGL(k_qkv, dim3(256, 2), dim3(256), 0, stream, x, Wt, Qb, Kb, Vt, sumsqp);
    hipLaunchKernelGGL(k_attn, dim3(16, 32), dim3(512), 0, stream, Qb, Kb, Vt, sumsqp, Ogb);
    hipLaunchKernelGGL(k_out, dim3(256, 2), dim3(256), 0, stream, Ogb, WoT, bout, out);
}

// Round 10
// 141.698 us; speedup vs baseline: 1.0010x; 1.0010x over previous
//
#include <hip/hip_runtime.h>

typedef short s16x8 __attribute__((ext_vector_type(8)));
typedef short s16x4 __attribute__((ext_vector_type(4)));
typedef float f32x4 __attribute__((ext_vector_type(4)));
typedef float f4 __attribute__((ext_vector_type(4)));
typedef unsigned short u16x4 __attribute__((ext_vector_type(4)));

#define CEXP 14.426950408889634074f   // 10 * log2(e)

__device__ __forceinline__ unsigned short f2bf(float f) {
    union { float f; unsigned int i; } v; v.f = f;
    unsigned int x = v.i;
    return (unsigned short)((x + 0x7fffu + ((x >> 16) & 1u)) >> 16);  // RNE
}
__device__ __forceinline__ float bf2f(unsigned short u) {
    union { unsigned int i; float f; } v; v.i = ((unsigned int)u) << 16; return v.f;
}

// pack 4 fp32 -> 4 bf16 (element order preserved)
__device__ __forceinline__ s16x4 pk_bf16x4(float p0, float p1, float p2, float p3) {
#if __has_builtin(__builtin_amdgcn_cvt_pk_bf16_f32)
    typedef __bf16 bf16x2 __attribute__((ext_vector_type(2)));
    union { struct { bf16x2 a, b; } h; s16x4 s; } r;
    r.h.a = __builtin_amdgcn_cvt_pk_bf16_f32(p0, p1);
    r.h.b = __builtin_amdgcn_cvt_pk_bf16_f32(p2, p3);
    return r.s;
#else
    unsigned u0 = __float_as_uint(p0) + 0x8000u;
    unsigned u1 = __float_as_uint(p1) + 0x8000u;
    unsigned u2 = __float_as_uint(p2) + 0x8000u;
    unsigned u3 = __float_as_uint(p3) + 0x8000u;
    union { uint2 u; s16x4 s; } pb;
    pb.u.x = __builtin_amdgcn_perm(u1, u0, 0x07060302u);
    pb.u.y = __builtin_amdgcn_perm(u3, u2, 0x07060302u);
    return pb.s;
#endif
}

__device__ __forceinline__ u16x4 pk4(f4 v) {
    u16x4 r = { f2bf(v[0]), f2bf(v[1]), f2bf(v[2]), f2bf(v[3]) };
    return r;
}

// global -> LDS direct DMA, 16B/lane.  HW semantics: LDS dest = wave-uniform
// base + lane*16 (exactly our staging layout); global src is per-lane.
__device__ __forceinline__ void gl_lds16(const void* g, void* l) {
    __builtin_amdgcn_global_load_lds(
        (const __attribute__((address_space(1))) void*)g,
        (__attribute__((address_space(3))) void*)l,
        16, 0, 0);
}

// ---------------------------------------------------------------------------
// k_prep v2 (unchanged): coalesced 64x64 LDS-tile transposes.
// ---------------------------------------------------------------------------
__global__ __launch_bounds__(256) void k_prep(
    const float* __restrict__ Wqkv, const float* __restrict__ Wout,
    unsigned short* __restrict__ Wt, unsigned short* __restrict__ WoT,
    float* __restrict__ sumsqp)
{
    __shared__ float tile[64][65];
    const int blk = blockIdx.x, tid = threadIdx.x;
    if (blk >= 16) {
        sumsqp[(blk - 16) * 256 + tid] = 0.f;     // 32 blocks x 256 = 8192
        return;
    }
    const float* src;
    unsigned short* dst;
    int lds_src, k0, n0;
    if (blk < 12) {
        src = Wqkv; dst = Wt; lds_src = 384;
        k0 = (blk & 1) * 64; n0 = (blk >> 1) * 64;
    } else {
        int b = blk - 12;
        src = Wout; dst = WoT; lds_src = 128;
        k0 = (b & 1) * 64; n0 = (b >> 1) * 64;
    }
    const int c = tid & 63, r0 = tid >> 6;
#pragma unroll
    for (int i = 0; i < 16; ++i) {
        int row = i * 4 + r0;
        tile[row][c] = src[(size_t)(k0 + row) * lds_src + n0 + c];
    }
    __syncthreads();
#pragma unroll
    for (int i = 0; i < 16; ++i) {
        int n = i * 4 + r0;
        dst[(size_t)(n0 + n) * 128 + k0 + c] = f2bf(tile[c][n]);
    }
}

// ---------------------------------------------------------------------------
// k_qkv v7 (unchanged from R19): 3-in-1, grid (256,2).
// ---------------------------------------------------------------------------
__global__ __launch_bounds__(256, 2) void k_qkv(
    const float* __restrict__ x, const unsigned short* __restrict__ Wt,
    unsigned short* __restrict__ Qb, unsigned short* __restrict__ Kb,
    unsigned short* __restrict__ Vt, float* __restrict__ sumsqp)
{
    __shared__ float red[4][64];
    const int tid = threadIdx.x;
    const int wl = tid >> 6, lane = tid & 63;
    const int qd = lane >> 4, nn = lane & 15;
    const int yb = blockIdx.y;                 // 0..1: 64-col half within category
    const int tw0 = blockIdx.x * 64 + wl * 16; // token base for this wave

    const float* apf = x + (size_t)(tw0 + nn) * 128 + qd * 8;
    s16x8 af[4];
#pragma unroll
    for (int ks = 0; ks < 4; ++ks) {
        f4 a0 = *(const f4*)(apf + ks * 32);
        f4 a1 = *(const f4*)(apf + ks * 32 + 4);
        union { struct { s16x4 lo, hi; } h; s16x8 v; } u;
        u.h.lo = pk_bf16x4(a0[0], a0[1], a0[2], a0[3]);
        u.h.hi = pk_bf16x4(a1[0], a1[1], a1[2], a1[3]);
        af[ks] = u.v;
    }

    const int b = tw0 >> 12;           // batch (block-uniform: 64 | 4096)
    const int tl0 = tw0 & 4095;        // token within batch
    const int tok = tl0 + nn;

    // ---- categories 0 (q) and 1 (k): A = W rows (out-cols), B = x rows ----
#pragma unroll
    for (int c = 0; c < 2; ++c) {
        const int n0 = c * 128 + yb * 64;
        const unsigned short* bp = Wt + (size_t)(n0 + nn) * 128 + qd * 8;
        s16x8 bfr[16];
#pragma unroll
        for (int nb = 0; nb < 4; ++nb)
#pragma unroll
            for (int ks = 0; ks < 4; ++ks)
                bfr[nb * 4 + ks] = *(const s16x8*)(bp + (size_t)nb * 2048 + ks * 32);

        f32x4 acc[4];
#pragma unroll
        for (int nb = 0; nb < 4; ++nb) acc[nb] = (f32x4){0.f, 0.f, 0.f, 0.f};
#pragma unroll
        for (int ks = 0; ks < 4; ++ks)
#pragma unroll
            for (int nb = 0; nb < 4; ++nb)
                acc[nb] = __builtin_amdgcn_mfma_f32_16x16x32_bf16(bfr[nb * 4 + ks], af[ks], acc[nb], 0, 0, 0);

        unsigned short* dst = (c == 0) ? Qb : Kb;
#pragma unroll
        for (int nb = 0; nb < 4; ++nb) {
            const int dim = yb * 64 + nb * 16 + qd * 4;      // 4-aligned, +r
            const int h = dim >> 5, d0 = dim & 31;
            *(u16x4*)&dst[(size_t)((b * 4 + h) * 4096 + tok) * 32 + d0] = pk4(acc[nb]);
            f32x4 ss;
#pragma unroll
            for (int r = 0; r < 4; ++r) ss[r] = acc[nb][r] * acc[nb][r];
#pragma unroll
            for (int m = 1; m < 16; m <<= 1) {
#pragma unroll
                for (int r = 0; r < 4; ++r) ss[r] += __shfl_xor(ss[r], m);
            }
            if (nn == 0)
                *(f4*)&red[wl][nb * 16 + qd * 4] = ss;       // slab partial
        }
        __syncthreads();                   // block-uniform: safe
        if (tid < 64) {
            float s = red[0][tid] + red[1][tid] + red[2][tid] + red[3][tid];
            const int g = (c << 9) + (b << 7) + yb * 64 + tid;
            atomicAdd(&sumsqp[((blockIdx.x & 7) << 10) + g], s);
        }
        __syncthreads();                   // red reused by next category
    }

    // ---- category 2 (v): A = x rows (tokens), B = W rows: D row = token ----
    {
        const int n0 = 256 + yb * 64;
        const unsigned short* bp = Wt + (size_t)(n0 + nn) * 128 + qd * 8;
        s16x8 bfr[16];
#pragma unroll
        for (int nb = 0; nb < 4; ++nb)
#pragma unroll
            for (int ks = 0; ks < 4; ++ks)
                bfr[nb * 4 + ks] = *(const s16x8*)(bp + (size_t)nb * 2048 + ks * 32);

        f32x4 acc[4];
#pragma unroll
        for (int nb = 0; nb < 4; ++nb) acc[nb] = (f32x4){0.f, 0.f, 0.f, 0.f};
#pragma unroll
        for (int ks = 0; ks < 4; ++ks)
#pragma unroll
            for (int nb = 0; nb < 4; ++nb)
                acc[nb] = __builtin_amdgcn_mfma_f32_16x16x32_bf16(af[ks], bfr[nb * 4 + ks], acc[nb], 0, 0, 0);
#pragma unroll
        for (int nb = 0; nb < 4; ++nb) {
            const int dim = yb * 64 + nb * 16 + nn;
            const int h = dim >> 5, d = dim & 31;
            *(u16x4*)&Vt[(size_t)((b * 4 + h) * 32 + d) * 4096 + tl0 + qd * 4] = pk4(acc[nb]);
        }
    }
}

// ---------------------------------------------------------------------------
// k_attn v17 = v16 with barrier every 2 jt (R21): per-CU per-jt-pair budget
// LDS ~1540 + MFMA ~1250 + VALU ~1300 cyc ~= 4330 wall -- three near-equal
// pipes SERIALIZE because the per-jt barrier re-aligns all 16 waves 32x:
// lockstep read-burst -> QK-burst -> exp-burst -> PV-burst.  Widening each
// dbuf slot to TWO tiles (LDS 32->64KB, still 2 blocks/CU: 128<=160KB)
// halves the lockstep events; between barriers waves drift up to a full
// tile apart so one wave's exp overlaps another's LDS/MFMA.  Per phase a
// wave issues 4 DMA loads then computes 2 tiles (~8600 cyc slack >> HBM
// latency).  Pipe totals, tile-internal layouts, compute and epilogue are
// byte-identical to v16/v13.
// ---------------------------------------------------------------------------
__global__ __launch_bounds__(512, 4) void k_attn(
    const unsigned short* __restrict__ Qb, const unsigned short* __restrict__ Kb,
    const unsigned short* __restrict__ Vt, const float* __restrict__ sumsqp,
    unsigned short* __restrict__ Ogb)
{
    __shared__ char smem[65536];
    const int tid  = threadIdx.x;
    const int wv   = tid >> 6, lane = tid & 63;
    const int wl   = wv & 3, half = wv >> 2;
    const int qd   = lane >> 4, nn = lane & 15;
    const int bh   = blockIdx.x;
    const int ib   = blockIdx.y * 128 + wl * 32;
    const unsigned short* Qbh = Qb + (size_t)bh * 4096 * 32;
    const unsigned short* Kbh = Kb + (size_t)bh * 4096 * 32;
    const unsigned short* Vbh = Vt + (size_t)bh * 32 * 4096;

    // rj[d] = min(rsqrt(ssq_q),1e12) * min(rsqrt(ssq_k),1e12) * CEXP
    float rj[8];
    {
        const int gq = bh * 32 + qd * 8;
#pragma unroll
        for (int j = 0; j < 8; ++j) {
            float sq = 0.f, sk = 0.f;
#pragma unroll
            for (int c = 0; c < 8; ++c) {
                sq += sumsqp[c * 1024 + gq + j];
                sk += sumsqp[c * 1024 + 512 + gq + j];
            }
            rj[j] = fminf(__builtin_amdgcn_rsqf(sq), 1e12f)
                  * fminf(__builtin_amdgcn_rsqf(sk), 1e12f) * CEXP;
        }
    }

    s16x8 q0r = *(const s16x8*)(Qbh + (ib + nn) * 32 + qd * 8);
    s16x8 q1r = *(const s16x8*)(Qbh + (ib + 16 + nn) * 32 + qd * 8);
    s16x8 qf0, qf1;
#pragma unroll
    for (int j = 0; j < 8; ++j) {
        qf0[j] = (short)f2bf(bf2f((unsigned short)q0r[j]) * rj[j]);
        qf1[j] = (short)f2bf(bf2f((unsigned short)q1r[j]) * rj[j]);
    }

    f32x4 o00 = {0.f,0.f,0.f,0.f}, o01 = {0.f,0.f,0.f,0.f};
    f32x4 o10 = {0.f,0.f,0.f,0.f}, o11 = {0.f,0.f,0.f,0.f};
    f32x4 la  = {0.f,0.f,0.f,0.f}, lb  = {0.f,0.f,0.f,0.f};
    const f32x4 zro = {0.f,0.f,0.f,0.f};
    const s16x8 ones8 = { (short)0x3F80, (short)0x3F80, (short)0x3F80, (short)0x3F80,
                          (short)0x3F80, (short)0x3F80, (short)0x3F80, (short)0x3F80 };

    // K region 32KB at +0: [half 16KB][slot 8KB][tile 4KB][wave 1KB]
    // V region 32KB at +32768: same geometry.
    const int KB0 = half * 16384;
    const int VB0 = 32768 + half * 16384;
    const int jb0 = half * 2048;

    // K staging: wave wl fills LDS tile-slot wl, rows nn, j-permuted
    const int jperm = ((wl >> 1) << 5) + ((nn >> 2) << 3) + ((wl & 1) << 2) + (nn & 3);
    const unsigned short* ksrc = Kbh + (size_t)(jb0 + jperm) * 32 + qd * 8;
    // V staging: wave wl -> (dhalf=wl>>1, js32=wl&1); lane: d=nn, tok=qd*8..+7
    const unsigned short* vsrc = Vbh + (size_t)((wl >> 1) * 16 + nn) * 4096
                               + jb0 + (wl & 1) * 32 + qd * 8;
    // wave-uniform DMA dest bases (HW adds lane*16)
    char* kbase = smem + KB0 + wl * 1024;
    char* vbase = smem + VB0 + wl * 1024;

    {   // preload tiles 0,1 -> slot 0 (drained by the loop's first barrier)
        gl_lds16(ksrc,        kbase);
        gl_lds16(ksrc + 2048, kbase + 4096);
        gl_lds16(vsrc,        vbase);
        gl_lds16(vsrc + 64,   vbase + 4096);
        ksrc += 4096; vsrc += 128;
    }

    for (int ph = 0; ph < 16; ++ph) {
        __syncthreads();   // drains DMA for slot ph&1; slot (ph+1)&1 free
        if (ph < 15) {
            const int nxt = ((ph + 1) & 1) * 8192;
            gl_lds16(ksrc,        kbase + nxt);
            gl_lds16(ksrc + 2048, kbase + nxt + 4096);
            gl_lds16(vsrc,        vbase + nxt);
            gl_lds16(vsrc + 64,   vbase + nxt + 4096);
            ksrc += 4096; vsrc += 128;
        }
        const char* kslot = smem + KB0 + (ph & 1) * 8192;
        const char* vslot = smem + VB0 + (ph & 1) * 8192;
#pragma unroll
        for (int t = 0; t < 2; ++t) {
            const char* kcur = kslot + t * 4096;
            const char* vcur = vslot + t * 4096;
#pragma unroll
            for (int js32 = 0; js32 < 2; ++js32) {
                s16x8 kf0 = *(const s16x8*)(kcur + (js32 * 2 + 0) * 1024 + lane * 16);
                s16x8 kf1 = *(const s16x8*)(kcur + (js32 * 2 + 1) * 1024 + lane * 16);
                f32x4 sa0 = __builtin_amdgcn_mfma_f32_16x16x32_bf16(kf0, qf0, zro, 0, 0, 0);
                f32x4 sb0 = __builtin_amdgcn_mfma_f32_16x16x32_bf16(kf0, qf1, zro, 0, 0, 0);
                f32x4 sa1 = __builtin_amdgcn_mfma_f32_16x16x32_bf16(kf1, qf0, zro, 0, 0, 0);
                f32x4 sb1 = __builtin_amdgcn_mfma_f32_16x16x32_bf16(kf1, qf1, zro, 0, 0, 0);
                float a0 = __builtin_amdgcn_exp2f(sa0[0]);
                float a1 = __builtin_amdgcn_exp2f(sa0[1]);
                float a2 = __builtin_amdgcn_exp2f(sa0[2]);
                float a3 = __builtin_amdgcn_exp2f(sa0[3]);
                float a4 = __builtin_amdgcn_exp2f(sa1[0]);
                float a5 = __builtin_amdgcn_exp2f(sa1[1]);
                float a6 = __builtin_amdgcn_exp2f(sa1[2]);
                float a7 = __builtin_amdgcn_exp2f(sa1[3]);
                float b0 = __builtin_amdgcn_exp2f(sb0[0]);
                float b1 = __builtin_amdgcn_exp2f(sb0[1]);
                float b2 = __builtin_amdgcn_exp2f(sb0[2]);
                float b3 = __builtin_amdgcn_exp2f(sb0[3]);
                float b4 = __builtin_amdgcn_exp2f(sb1[0]);
                float b5 = __builtin_amdgcn_exp2f(sb1[1]);
                float b6 = __builtin_amdgcn_exp2f(sb1[2]);
                float b7 = __builtin_amdgcn_exp2f(sb1[3]);
                union { struct { s16x4 lo, hi; } h; s16x8 v; } ua, ub;
                ua.h.lo = pk_bf16x4(a0, a1, a2, a3);
                ua.h.hi = pk_bf16x4(a4, a5, a6, a7);
                ub.h.lo = pk_bf16x4(b0, b1, b2, b3);
                ub.h.hi = pk_bf16x4(b4, b5, b6, b7);
                s16x8 pa32 = ua.v, pb32 = ub.v;
                la = __builtin_amdgcn_mfma_f32_16x16x32_bf16(ones8, pa32, la, 0, 0, 0);
                lb = __builtin_amdgcn_mfma_f32_16x16x32_bf16(ones8, pb32, lb, 0, 0, 0);
                s16x8 va = *(const s16x8*)(vcur + js32 * 1024 + lane * 16);
                s16x8 vb = *(const s16x8*)(vcur + 2048 + js32 * 1024 + lane * 16);
                o00 = __builtin_amdgcn_mfma_f32_16x16x32_bf16(va, pa32, o00, 0, 0, 0);
                o01 = __builtin_amdgcn_mfma_f32_16x16x32_bf16(vb, pa32, o01, 0, 0, 0);
                o10 = __builtin_amdgcn_mfma_f32_16x16x32_bf16(va, pb32, o10, 0, 0, 0);
                o11 = __builtin_amdgcn_mfma_f32_16x16x32_bf16(vb, pb32, o11, 0, 0, 0);
            }
        }
    }

    const float lpa = la[0];   // replicated over r and qd; exact row-sum for i=nn
    const float lpb = lb[0];
    __syncthreads();                           // staging LDS dead now
    float* Ob = (float*)smem;                  // [4 wl][2 it][64 lane][8] = 16KB
    float* Lb = (float*)(smem + 16384);        // [4][2][64] = 2KB
    if (half) {
        float* d0 = Ob + ((wl * 2 + 0) * 64 + lane) * 8;
        *(f4*)d0 = o00; *(f4*)(d0 + 4) = o01;
        float* d1 = Ob + ((wl * 2 + 1) * 64 + lane) * 8;
        *(f4*)d1 = o10; *(f4*)(d1 + 4) = o11;
        Lb[(wl * 2 + 0) * 64 + lane] = lpa;
        Lb[(wl * 2 + 1) * 64 + lane] = lpb;
    }
    __syncthreads();
    if (!half) {
        const int bb = bh >> 2, hh = bh & 3;
        float* s0 = Ob + ((wl * 2 + 0) * 64 + lane) * 8;
        float rla = 1.f / (lpa + Lb[(wl * 2 + 0) * 64 + lane]);
        f4 m00 = (o00 + *(const f4*)s0) * rla;
        f4 m01 = (o01 + *(const f4*)(s0 + 4)) * rla;
        float* s1 = Ob + ((wl * 2 + 1) * 64 + lane) * 8;
        float rlb = 1.f / (lpb + Lb[(wl * 2 + 1) * 64 + lane]);
        f4 m10 = (o10 + *(const f4*)s1) * rlb;
        f4 m11 = (o11 + *(const f4*)(s1 + 4)) * rlb;
        unsigned short* dst0 = Ogb + (size_t)(bb * 4096 + blockIdx.y * 128 + wl * 32 + nn) * 128
                             + hh * 32 + qd * 4;
        *(u16x4*)dst0 = pk4(m00);
        *(u16x4*)(dst0 + 16) = pk4(m01);
        unsigned short* dst1 = dst0 + (size_t)16 * 128;
        *(u16x4*)dst1 = pk4(m10);
        *(u16x4*)(dst1 + 16) = pk4(m11);
    }
}

// ---------------------------------------------------------------------------
// k_out v1 (unchanged): out = Og @ W_out + b_out.
// ---------------------------------------------------------------------------
__global__ __launch_bounds__(256, 2) void k_out(
    const unsigned short* __restrict__ Ogb, const unsigned short* __restrict__ WoT,
    const float* __restrict__ bout, float* __restrict__ out)
{
    const int tid = threadIdx.x;
    const int wl = tid >> 6, lane = tid & 63;
    const int qd = lane >> 4, nn = lane & 15;
    const int n0 = blockIdx.y * 64;            // outc base
    const int tw0 = blockIdx.x * 64 + wl * 16; // token base

    const unsigned short* ap = WoT + (size_t)(n0 + nn) * 128 + qd * 8;
    const unsigned short* bp = Ogb + (size_t)(tw0 + nn) * 128 + qd * 8;
    s16x8 bfr[4], afr[16];
#pragma unroll
    for (int ks = 0; ks < 4; ++ks) bfr[ks] = *(const s16x8*)(bp + ks * 32);
#pragma unroll
    for (int nb = 0; nb < 4; ++nb)
#pragma unroll
        for (int ks = 0; ks < 4; ++ks)
            afr[nb * 4 + ks] = *(const s16x8*)(ap + (size_t)nb * 2048 + ks * 32);

    f32x4 acc[4];
#pragma unroll
    for (int nb = 0; nb < 4; ++nb) acc[nb] = (f32x4){0.f, 0.f, 0.f, 0.f};
#pragma unroll
    for (int ks = 0; ks < 4; ++ks)
#pragma unroll
        for (int nb = 0; nb < 4; ++nb)
            acc[nb] = __builtin_amdgcn_mfma_f32_16x16x32_bf16(afr[nb * 4 + ks], bfr[ks], acc[nb], 0, 0, 0);

#pragma unroll
    for (int nb = 0; nb < 4; ++nb) {
        const int c = n0 + nb * 16 + qd * 4;
        f4 bv = *(const f4*)&bout[c];
        f4 r;
#pragma unroll
        for (int j = 0; j < 4; ++j) r[j] = acc[nb][j] + bv[j];
        *(f4*)&out[(size_t)(tw0 + nn) * 128 + c] = r;
    }
}

// ---------------------------------------------------------------------------
extern "C" void kernel_launch(void* const* d_in, const int* in_sizes, int n_in,
                              void* d_out, int out_size, void* d_ws, size_t ws_size,
                              hipStream_t stream)
{
    const float* x    = (const float*)d_in[0];
    const float* Wqkv = (const float*)d_in[1];
    const float* Wout = (const float*)d_in[2];
    const float* bout = (const float*)d_in[3];
    float* out = (float*)d_out;
    char* ws = (char*)d_ws;
    const size_t MB = 1024 * 1024;
    unsigned short* Qb  = (unsigned short*)(ws);             // 4 MB [16][4096][32] (raw q)
    unsigned short* Kb  = (unsigned short*)(ws + 4 * MB);    // 4 MB (raw k)
    unsigned short* Vt  = (unsigned short*)(ws + 8 * MB);    // 4 MB [16][32][4096]
    unsigned short* Ogb = (unsigned short*)(ws + 12 * MB);   // 4 MB [16384][128] bf16
    unsigned short* Wt  = (unsigned short*)(ws + 16 * MB);               // 96 KB
    unsigned short* WoT = (unsigned short*)(ws + 16 * MB + 112 * 1024);  // 32 KB
    float*       sumsqp = (float*)(ws + 16 * MB + 160 * 1024);           // 32 KB [8][1024]

    hipLaunchKernelGGL(k_prep, dim3(48), dim3(256), 0, stream, Wqkv, Wout, Wt, WoT, sumsqp);
    hipLaunchKernelGGL(k_qkv, dim3(256, 2), dim3(256), 0, stream, x, Wt, Qb, Kb, Vt, sumsqp);
    hipLaunchKernelGGL(k_attn, dim3(16, 32), dim3(512), 0, stream, Qb, Kb, Vt, sumsqp, Ogb);
    hipLaunchKernelGGL(k_out, dim3(256, 2), dim3(256), 0, stream, Ogb, WoT, bout, out);
}

// Round 11
// 141.618 us; speedup vs baseline: 1.0016x; 1.0006x over previous
//
#include <hip/hip_runtime.h>

typedef short s16x8 __attribute__((ext_vector_type(8)));
typedef short s16x4 __attribute__((ext_vector_type(4)));
typedef float f32x4 __attribute__((ext_vector_type(4)));
typedef float f4 __attribute__((ext_vector_type(4)));
typedef unsigned short u16x4 __attribute__((ext_vector_type(4)));

#define CEXP 14.426950408889634074f   // 10 * log2(e)

__device__ __forceinline__ unsigned short f2bf(float f) {
    union { float f; unsigned int i; } v; v.f = f;
    unsigned int x = v.i;
    return (unsigned short)((x + 0x7fffu + ((x >> 16) & 1u)) >> 16);  // RNE
}
__device__ __forceinline__ float bf2f(unsigned short u) {
    union { unsigned int i; float f; } v; v.i = ((unsigned int)u) << 16; return v.f;
}

// pack 4 fp32 -> 4 bf16 (element order preserved)
__device__ __forceinline__ s16x4 pk_bf16x4(float p0, float p1, float p2, float p3) {
#if __has_builtin(__builtin_amdgcn_cvt_pk_bf16_f32)
    typedef __bf16 bf16x2 __attribute__((ext_vector_type(2)));
    union { struct { bf16x2 a, b; } h; s16x4 s; } r;
    r.h.a = __builtin_amdgcn_cvt_pk_bf16_f32(p0, p1);
    r.h.b = __builtin_amdgcn_cvt_pk_bf16_f32(p2, p3);
    return r.s;
#else
    unsigned u0 = __float_as_uint(p0) + 0x8000u;
    unsigned u1 = __float_as_uint(p1) + 0x8000u;
    unsigned u2 = __float_as_uint(p2) + 0x8000u;
    unsigned u3 = __float_as_uint(p3) + 0x8000u;
    union { uint2 u; s16x4 s; } pb;
    pb.u.x = __builtin_amdgcn_perm(u1, u0, 0x07060302u);
    pb.u.y = __builtin_amdgcn_perm(u3, u2, 0x07060302u);
    return pb.s;
#endif
}

__device__ __forceinline__ u16x4 pk4(f4 v) {
    u16x4 r = { f2bf(v[0]), f2bf(v[1]), f2bf(v[2]), f2bf(v[3]) };
    return r;
}

// global -> LDS direct DMA, 16B/lane.  HW semantics: LDS dest = wave-uniform
// base + lane*16 (exactly our staging layout); global src is per-lane.
__device__ __forceinline__ void gl_lds16(const void* g, void* l) {
    __builtin_amdgcn_global_load_lds(
        (const __attribute__((address_space(1))) void*)g,
        (__attribute__((address_space(3))) void*)l,
        16, 0, 0);
}

// ---------------------------------------------------------------------------
// k_prep v2 (unchanged): coalesced 64x64 LDS-tile transposes.
// ---------------------------------------------------------------------------
__global__ __launch_bounds__(256) void k_prep(
    const float* __restrict__ Wqkv, const float* __restrict__ Wout,
    unsigned short* __restrict__ Wt, unsigned short* __restrict__ WoT,
    float* __restrict__ sumsqp)
{
    __shared__ float tile[64][65];
    const int blk = blockIdx.x, tid = threadIdx.x;
    if (blk >= 16) {
        sumsqp[(blk - 16) * 256 + tid] = 0.f;     // 32 blocks x 256 = 8192
        return;
    }
    const float* src;
    unsigned short* dst;
    int lds_src, k0, n0;
    if (blk < 12) {
        src = Wqkv; dst = Wt; lds_src = 384;
        k0 = (blk & 1) * 64; n0 = (blk >> 1) * 64;
    } else {
        int b = blk - 12;
        src = Wout; dst = WoT; lds_src = 128;
        k0 = (b & 1) * 64; n0 = (b >> 1) * 64;
    }
    const int c = tid & 63, r0 = tid >> 6;
#pragma unroll
    for (int i = 0; i < 16; ++i) {
        int row = i * 4 + r0;
        tile[row][c] = src[(size_t)(k0 + row) * lds_src + n0 + c];
    }
    __syncthreads();
#pragma unroll
    for (int i = 0; i < 16; ++i) {
        int n = i * 4 + r0;
        dst[(size_t)(n0 + n) * 128 + k0 + c] = f2bf(tile[c][n]);
    }
}

// ---------------------------------------------------------------------------
// k_qkv v7 (unchanged from R19): 3-in-1, grid (256,2).
// ---------------------------------------------------------------------------
__global__ __launch_bounds__(256, 2) void k_qkv(
    const float* __restrict__ x, const unsigned short* __restrict__ Wt,
    unsigned short* __restrict__ Qb, unsigned short* __restrict__ Kb,
    unsigned short* __restrict__ Vt, float* __restrict__ sumsqp)
{
    __shared__ float red[4][64];
    const int tid = threadIdx.x;
    const int wl = tid >> 6, lane = tid & 63;
    const int qd = lane >> 4, nn = lane & 15;
    const int yb = blockIdx.y;                 // 0..1: 64-col half within category
    const int tw0 = blockIdx.x * 64 + wl * 16; // token base for this wave

    const float* apf = x + (size_t)(tw0 + nn) * 128 + qd * 8;
    s16x8 af[4];
#pragma unroll
    for (int ks = 0; ks < 4; ++ks) {
        f4 a0 = *(const f4*)(apf + ks * 32);
        f4 a1 = *(const f4*)(apf + ks * 32 + 4);
        union { struct { s16x4 lo, hi; } h; s16x8 v; } u;
        u.h.lo = pk_bf16x4(a0[0], a0[1], a0[2], a0[3]);
        u.h.hi = pk_bf16x4(a1[0], a1[1], a1[2], a1[3]);
        af[ks] = u.v;
    }

    const int b = tw0 >> 12;           // batch (block-uniform: 64 | 4096)
    const int tl0 = tw0 & 4095;        // token within batch
    const int tok = tl0 + nn;

    // ---- categories 0 (q) and 1 (k): A = W rows (out-cols), B = x rows ----
#pragma unroll
    for (int c = 0; c < 2; ++c) {
        const int n0 = c * 128 + yb * 64;
        const unsigned short* bp = Wt + (size_t)(n0 + nn) * 128 + qd * 8;
        s16x8 bfr[16];
#pragma unroll
        for (int nb = 0; nb < 4; ++nb)
#pragma unroll
            for (int ks = 0; ks < 4; ++ks)
                bfr[nb * 4 + ks] = *(const s16x8*)(bp + (size_t)nb * 2048 + ks * 32);

        f32x4 acc[4];
#pragma unroll
        for (int nb = 0; nb < 4; ++nb) acc[nb] = (f32x4){0.f, 0.f, 0.f, 0.f};
#pragma unroll
        for (int ks = 0; ks < 4; ++ks)
#pragma unroll
            for (int nb = 0; nb < 4; ++nb)
                acc[nb] = __builtin_amdgcn_mfma_f32_16x16x32_bf16(bfr[nb * 4 + ks], af[ks], acc[nb], 0, 0, 0);

        unsigned short* dst = (c == 0) ? Qb : Kb;
#pragma unroll
        for (int nb = 0; nb < 4; ++nb) {
            const int dim = yb * 64 + nb * 16 + qd * 4;      // 4-aligned, +r
            const int h = dim >> 5, d0 = dim & 31;
            *(u16x4*)&dst[(size_t)((b * 4 + h) * 4096 + tok) * 32 + d0] = pk4(acc[nb]);
            f32x4 ss;
#pragma unroll
            for (int r = 0; r < 4; ++r) ss[r] = acc[nb][r] * acc[nb][r];
#pragma unroll
            for (int m = 1; m < 16; m <<= 1) {
#pragma unroll
                for (int r = 0; r < 4; ++r) ss[r] += __shfl_xor(ss[r], m);
            }
            if (nn == 0)
                *(f4*)&red[wl][nb * 16 + qd * 4] = ss;       // slab partial
        }
        __syncthreads();                   // block-uniform: safe
        if (tid < 64) {
            float s = red[0][tid] + red[1][tid] + red[2][tid] + red[3][tid];
            const int g = (c << 9) + (b << 7) + yb * 64 + tid;
            atomicAdd(&sumsqp[((blockIdx.x & 7) << 10) + g], s);
        }
        __syncthreads();                   // red reused by next category
    }

    // ---- category 2 (v): A = x rows (tokens), B = W rows: D row = token ----
    {
        const int n0 = 256 + yb * 64;
        const unsigned short* bp = Wt + (size_t)(n0 + nn) * 128 + qd * 8;
        s16x8 bfr[16];
#pragma unroll
        for (int nb = 0; nb < 4; ++nb)
#pragma unroll
            for (int ks = 0; ks < 4; ++ks)
                bfr[nb * 4 + ks] = *(const s16x8*)(bp + (size_t)nb * 2048 + ks * 32);

        f32x4 acc[4];
#pragma unroll
        for (int nb = 0; nb < 4; ++nb) acc[nb] = (f32x4){0.f, 0.f, 0.f, 0.f};
#pragma unroll
        for (int ks = 0; ks < 4; ++ks)
#pragma unroll
            for (int nb = 0; nb < 4; ++nb)
                acc[nb] = __builtin_amdgcn_mfma_f32_16x16x32_bf16(af[ks], bfr[nb * 4 + ks], acc[nb], 0, 0, 0);
#pragma unroll
        for (int nb = 0; nb < 4; ++nb) {
            const int dim = yb * 64 + nb * 16 + nn;
            const int h = dim >> 5, d = dim & 31;
            *(u16x4*)&Vt[(size_t)((b * 4 + h) * 32 + d) * 4096 + tl0 + qd * 4] = pk4(acc[nb]);
        }
    }
}

// ---------------------------------------------------------------------------
// k_attn v18 = v17 + explicit 1-step software pipeline (R22).  Ledger:
// occupancy (18/33/46/69%), LDS traffic (-50%), conflicts (-44x), barrier
// cadence (-50%), DMA staging -- ALL neutral around ~58us; pipes 29% MFMA /
// 26% VALU / 35% LDS, ~45% issue slots dead => in-wave serial chain
// ds_read->QK->exp->pack->PV (~350cyc) is the wall and 4 waves don't cover
// it.  Pipeline: carry QK results (sa*p) + V frags (vap/vbp) of step s-1 in
// registers; each step issues its 4 ds_reads, FINISHES step s-1 (exp/pack/
// 6 MFMA, register-only -- read latency hides under it), then QKs step s
// (results consumed a full iteration later).  Primed with sa*p=-1e30
// (exp2->0: dummy finish adds exact zeros, no branches), drained by one
// final finish.  Cross-barrier state = registers only; every LDS read stays
// in its owning phase, so v17's dbuf race discipline is untouched.
// +~28 VGPR (-> ~90 < 128 cap at 4 waves/EU).
// ---------------------------------------------------------------------------
__global__ __launch_bounds__(512, 4) void k_attn(
    const unsigned short* __restrict__ Qb, const unsigned short* __restrict__ Kb,
    const unsigned short* __restrict__ Vt, const float* __restrict__ sumsqp,
    unsigned short* __restrict__ Ogb)
{
    __shared__ char smem[65536];
    const int tid  = threadIdx.x;
    const int wv   = tid >> 6, lane = tid & 63;
    const int wl   = wv & 3, half = wv >> 2;
    const int qd   = lane >> 4, nn = lane & 15;
    const int bh   = blockIdx.x;
    const int ib   = blockIdx.y * 128 + wl * 32;
    const unsigned short* Qbh = Qb + (size_t)bh * 4096 * 32;
    const unsigned short* Kbh = Kb + (size_t)bh * 4096 * 32;
    const unsigned short* Vbh = Vt + (size_t)bh * 32 * 4096;

    // rj[d] = min(rsqrt(ssq_q),1e12) * min(rsqrt(ssq_k),1e12) * CEXP
    float rj[8];
    {
        const int gq = bh * 32 + qd * 8;
#pragma unroll
        for (int j = 0; j < 8; ++j) {
            float sq = 0.f, sk = 0.f;
#pragma unroll
            for (int c = 0; c < 8; ++c) {
                sq += sumsqp[c * 1024 + gq + j];
                sk += sumsqp[c * 1024 + 512 + gq + j];
            }
            rj[j] = fminf(__builtin_amdgcn_rsqf(sq), 1e12f)
                  * fminf(__builtin_amdgcn_rsqf(sk), 1e12f) * CEXP;
        }
    }

    s16x8 q0r = *(const s16x8*)(Qbh + (ib + nn) * 32 + qd * 8);
    s16x8 q1r = *(const s16x8*)(Qbh + (ib + 16 + nn) * 32 + qd * 8);
    s16x8 qf0, qf1;
#pragma unroll
    for (int j = 0; j < 8; ++j) {
        qf0[j] = (short)f2bf(bf2f((unsigned short)q0r[j]) * rj[j]);
        qf1[j] = (short)f2bf(bf2f((unsigned short)q1r[j]) * rj[j]);
    }

    f32x4 o00 = {0.f,0.f,0.f,0.f}, o01 = {0.f,0.f,0.f,0.f};
    f32x4 o10 = {0.f,0.f,0.f,0.f}, o11 = {0.f,0.f,0.f,0.f};
    f32x4 la  = {0.f,0.f,0.f,0.f}, lb  = {0.f,0.f,0.f,0.f};
    const f32x4 zro = {0.f,0.f,0.f,0.f};
    const s16x8 ones8 = { (short)0x3F80, (short)0x3F80, (short)0x3F80, (short)0x3F80,
                          (short)0x3F80, (short)0x3F80, (short)0x3F80, (short)0x3F80 };

    // pipeline state: QK results + V fragments of the PREVIOUS step.
    // -1e30 -> exp2 = 0 -> dummy first finish contributes exact zeros.
    f32x4 sa0p = {-1e30f,-1e30f,-1e30f,-1e30f};
    f32x4 sa1p = {-1e30f,-1e30f,-1e30f,-1e30f};
    f32x4 sb0p = {-1e30f,-1e30f,-1e30f,-1e30f};
    f32x4 sb1p = {-1e30f,-1e30f,-1e30f,-1e30f};
    s16x8 vap = {0,0,0,0,0,0,0,0};
    s16x8 vbp = {0,0,0,0,0,0,0,0};

#define FINISH_PREV() do {                                                    \
    float a0 = __builtin_amdgcn_exp2f(sa0p[0]);                               \
    float a1 = __builtin_amdgcn_exp2f(sa0p[1]);                               \
    float a2 = __builtin_amdgcn_exp2f(sa0p[2]);                               \
    float a3 = __builtin_amdgcn_exp2f(sa0p[3]);                               \
    float a4 = __builtin_amdgcn_exp2f(sa1p[0]);                               \
    float a5 = __builtin_amdgcn_exp2f(sa1p[1]);                               \
    float a6 = __builtin_amdgcn_exp2f(sa1p[2]);                               \
    float a7 = __builtin_amdgcn_exp2f(sa1p[3]);                               \
    float b0 = __builtin_amdgcn_exp2f(sb0p[0]);                               \
    float b1 = __builtin_amdgcn_exp2f(sb0p[1]);                               \
    float b2 = __builtin_amdgcn_exp2f(sb0p[2]);                               \
    float b3 = __builtin_amdgcn_exp2f(sb0p[3]);                               \
    float b4 = __builtin_amdgcn_exp2f(sb1p[0]);                               \
    float b5 = __builtin_amdgcn_exp2f(sb1p[1]);                               \
    float b6 = __builtin_amdgcn_exp2f(sb1p[2]);                               \
    float b7 = __builtin_amdgcn_exp2f(sb1p[3]);                               \
    union { struct { s16x4 lo, hi; } h; s16x8 v; } ua, ub;                    \
    ua.h.lo = pk_bf16x4(a0, a1, a2, a3);                                      \
    ua.h.hi = pk_bf16x4(a4, a5, a6, a7);                                      \
    ub.h.lo = pk_bf16x4(b0, b1, b2, b3);                                      \
    ub.h.hi = pk_bf16x4(b4, b5, b6, b7);                                      \
    s16x8 pa32 = ua.v, pb32 = ub.v;                                           \
    la  = __builtin_amdgcn_mfma_f32_16x16x32_bf16(ones8, pa32, la, 0, 0, 0);  \
    lb  = __builtin_amdgcn_mfma_f32_16x16x32_bf16(ones8, pb32, lb, 0, 0, 0);  \
    o00 = __builtin_amdgcn_mfma_f32_16x16x32_bf16(vap, pa32, o00, 0, 0, 0);   \
    o01 = __builtin_amdgcn_mfma_f32_16x16x32_bf16(vbp, pa32, o01, 0, 0, 0);   \
    o10 = __builtin_amdgcn_mfma_f32_16x16x32_bf16(vap, pb32, o10, 0, 0, 0);   \
    o11 = __builtin_amdgcn_mfma_f32_16x16x32_bf16(vbp, pb32, o11, 0, 0, 0);   \
} while (0)

#define ATTN_STEP(kc, vc, js) do {                                            \
    s16x8 kf0 = *(const s16x8*)((kc) + ((js) * 2 + 0) * 1024 + lane * 16);    \
    s16x8 kf1 = *(const s16x8*)((kc) + ((js) * 2 + 1) * 1024 + lane * 16);    \
    s16x8 van = *(const s16x8*)((vc) + (js) * 1024 + lane * 16);              \
    s16x8 vbn = *(const s16x8*)((vc) + 2048 + (js) * 1024 + lane * 16);       \
    FINISH_PREV();                                                            \
    sa0p = __builtin_amdgcn_mfma_f32_16x16x32_bf16(kf0, qf0, zro, 0, 0, 0);   \
    sb0p = __builtin_amdgcn_mfma_f32_16x16x32_bf16(kf0, qf1, zro, 0, 0, 0);   \
    sa1p = __builtin_amdgcn_mfma_f32_16x16x32_bf16(kf1, qf0, zro, 0, 0, 0);   \
    sb1p = __builtin_amdgcn_mfma_f32_16x16x32_bf16(kf1, qf1, zro, 0, 0, 0);   \
    vap = van; vbp = vbn;                                                     \
} while (0)

    // K region 32KB at +0: [half 16KB][slot 8KB][tile 4KB][wave 1KB]
    // V region 32KB at +32768: same geometry.
    const int KB0 = half * 16384;
    const int VB0 = 32768 + half * 16384;
    const int jb0 = half * 2048;

    // K staging: wave wl fills LDS tile-slot wl, rows nn, j-permuted
    const int jperm = ((wl >> 1) << 5) + ((nn >> 2) << 3) + ((wl & 1) << 2) + (nn & 3);
    const unsigned short* ksrc = Kbh + (size_t)(jb0 + jperm) * 32 + qd * 8;
    // V staging: wave wl -> (dhalf=wl>>1, js32=wl&1); lane: d=nn, tok=qd*8..+7
    const unsigned short* vsrc = Vbh + (size_t)((wl >> 1) * 16 + nn) * 4096
                               + jb0 + (wl & 1) * 32 + qd * 8;
    // wave-uniform DMA dest bases (HW adds lane*16)
    char* kbase = smem + KB0 + wl * 1024;
    char* vbase = smem + VB0 + wl * 1024;

    {   // preload tiles 0,1 -> slot 0 (drained by the loop's first barrier)
        gl_lds16(ksrc,        kbase);
        gl_lds16(ksrc + 2048, kbase + 4096);
        gl_lds16(vsrc,        vbase);
        gl_lds16(vsrc + 64,   vbase + 4096);
        ksrc += 4096; vsrc += 128;
    }

    for (int ph = 0; ph < 16; ++ph) {
        __syncthreads();   // drains DMA for slot ph&1; slot (ph+1)&1 free
        if (ph < 15) {
            const int nxt = ((ph + 1) & 1) * 8192;
            gl_lds16(ksrc,        kbase + nxt);
            gl_lds16(ksrc + 2048, kbase + nxt + 4096);
            gl_lds16(vsrc,        vbase + nxt);
            gl_lds16(vsrc + 64,   vbase + nxt + 4096);
            ksrc += 4096; vsrc += 128;
        }
        const char* kslot = smem + KB0 + (ph & 1) * 8192;
        const char* vslot = smem + VB0 + (ph & 1) * 8192;
        ATTN_STEP(kslot,        vslot,        0);
        ATTN_STEP(kslot,        vslot,        1);
        ATTN_STEP(kslot + 4096, vslot + 4096, 0);
        ATTN_STEP(kslot + 4096, vslot + 4096, 1);
    }
    FINISH_PREV();   // drain the last step

#undef ATTN_STEP
#undef FINISH_PREV

    const float lpa = la[0];   // replicated over r and qd; exact row-sum for i=nn
    const float lpb = lb[0];
    __syncthreads();                           // staging LDS dead now
    float* Ob = (float*)smem;                  // [4 wl][2 it][64 lane][8] = 16KB
    float* Lb = (float*)(smem + 16384);        // [4][2][64] = 2KB
    if (half) {
        float* d0 = Ob + ((wl * 2 + 0) * 64 + lane) * 8;
        *(f4*)d0 = o00; *(f4*)(d0 + 4) = o01;
        float* d1 = Ob + ((wl * 2 + 1) * 64 + lane) * 8;
        *(f4*)d1 = o10; *(f4*)(d1 + 4) = o11;
        Lb[(wl * 2 + 0) * 64 + lane] = lpa;
        Lb[(wl * 2 + 1) * 64 + lane] = lpb;
    }
    __syncthreads();
    if (!half) {
        const int bb = bh >> 2, hh = bh & 3;
        float* s0 = Ob + ((wl * 2 + 0) * 64 + lane) * 8;
        float rla = 1.f / (lpa + Lb[(wl * 2 + 0) * 64 + lane]);
        f4 m00 = (o00 + *(const f4*)s0) * rla;
        f4 m01 = (o01 + *(const f4*)(s0 + 4)) * rla;
        float* s1 = Ob + ((wl * 2 + 1) * 64 + lane) * 8;
        float rlb = 1.f / (lpb + Lb[(wl * 2 + 1) * 64 + lane]);
        f4 m10 = (o10 + *(const f4*)s1) * rlb;
        f4 m11 = (o11 + *(const f4*)(s1 + 4)) * rlb;
        unsigned short* dst0 = Ogb + (size_t)(bb * 4096 + blockIdx.y * 128 + wl * 32 + nn) * 128
                             + hh * 32 + qd * 4;
        *(u16x4*)dst0 = pk4(m00);
        *(u16x4*)(dst0 + 16) = pk4(m01);
        unsigned short* dst1 = dst0 + (size_t)16 * 128;
        *(u16x4*)dst1 = pk4(m10);
        *(u16x4*)(dst1 + 16) = pk4(m11);
    }
}

// ---------------------------------------------------------------------------
// k_out v1 (unchanged): out = Og @ W_out + b_out.
// ---------------------------------------------------------------------------
__global__ __launch_bounds__(256, 2) void k_out(
    const unsigned short* __restrict__ Ogb, const unsigned short* __restrict__ WoT,
    const float* __restrict__ bout, float* __restrict__ out)
{
    const int tid = threadIdx.x;
    const int wl = tid >> 6, lane = tid & 63;
    const int qd = lane >> 4, nn = lane & 15;
    const int n0 = blockIdx.y * 64;            // outc base
    const int tw0 = blockIdx.x * 64 + wl * 16; // token base

    const unsigned short* ap = WoT + (size_t)(n0 + nn) * 128 + qd * 8;
    const unsigned short* bp = Ogb + (size_t)(tw0 + nn) * 128 + qd * 8;
    s16x8 bfr[4], afr[16];
#pragma unroll
    for (int ks = 0; ks < 4; ++ks) bfr[ks] = *(const s16x8*)(bp + ks * 32);
#pragma unroll
    for (int nb = 0; nb < 4; ++nb)
#pragma unroll
        for (int ks = 0; ks < 4; ++ks)
            afr[nb * 4 + ks] = *(const s16x8*)(ap + (size_t)nb * 2048 + ks * 32);

    f32x4 acc[4];
#pragma unroll
    for (int nb = 0; nb < 4; ++nb) acc[nb] = (f32x4){0.f, 0.f, 0.f, 0.f};
#pragma unroll
    for (int ks = 0; ks < 4; ++ks)
#pragma unroll
        for (int nb = 0; nb < 4; ++nb)
            acc[nb] = __builtin_amdgcn_mfma_f32_16x16x32_bf16(afr[nb * 4 + ks], bfr[ks], acc[nb], 0, 0, 0);

#pragma unroll
    for (int nb = 0; nb < 4; ++nb) {
        const int c = n0 + nb * 16 + qd * 4;
        f4 bv = *(const f4*)&bout[c];
        f4 r;
#pragma unroll
        for (int j = 0; j < 4; ++j) r[j] = acc[nb][j] + bv[j];
        *(f4*)&out[(size_t)(tw0 + nn) * 128 + c] = r;
    }
}

// ---------------------------------------------------------------------------
extern "C" void kernel_launch(void* const* d_in, const int* in_sizes, int n_in,
                              void* d_out, int out_size, void* d_ws, size_t ws_size,
                              hipStream_t stream)
{
    const float* x    = (const float*)d_in[0];
    const float* Wqkv = (const float*)d_in[1];
    const float* Wout = (const float*)d_in[2];
    const float* bout = (const float*)d_in[3];
    float* out = (float*)d_out;
    char* ws = (char*)d_ws;
    const size_t MB = 1024 * 1024;
    unsigned short* Qb  = (unsigned short*)(ws);             // 4 MB [16][4096][32] (raw q)
    unsigned short* Kb  = (unsigned short*)(ws + 4 * MB);    // 4 MB (raw k)
    unsigned short* Vt  = (unsigned short*)(ws + 8 * MB);    // 4 MB [16][32][4096]
    unsigned short* Ogb = (unsigned short*)(ws + 12 * MB);   // 4 MB [16384][128] bf16
    unsigned short* Wt  = (unsigned short*)(ws + 16 * MB);               // 96 KB
    unsigned short* WoT = (unsigned short*)(ws + 16 * MB + 112 * 1024);  // 32 KB
    float*       sumsqp = (float*)(ws + 16 * MB + 160 * 1024);           // 32 KB [8][1024]

    hipLaunchKernelGGL(k_prep, dim3(48), dim3(256), 0, stream, Wqkv, Wout, Wt, WoT, sumsqp);
    hipLaunchKernelGGL(k_qkv, dim3(256, 2), dim3(256), 0, stream, x, Wt, Qb, Kb, Vt, sumsqp);
    hipLaunchKernelGGL(k_attn, dim3(16, 32), dim3(512), 0, stream, Qb, Kb, Vt, sumsqp, Ogb);
    hipLaunchKernelGGL(k_out, dim3(256, 2), dim3(256), 0, stream, Ogb, WoT, bout, out);
}